// Round 12
// baseline (406.240 us; speedup 1.0000x reference)
//
#include <hip/hip_runtime.h>
#include <math.h>

// RoutingLayer fused via split-fp16 MFMA emulation of fp32 GEMM.
// routing = x@w_gate + noise*(softplus(x@w_noise)+0.01); out = scatter(softmax(top2)).
// x: 32768x2048 fp32, w_*: 2048x64 fp32, noise: 32768x64, out: 32768x64.
//
// R15: m97's shape -- 4 SMALL independent barrier groups per CU. R4-R14
// falsified depth/occupancy/barrier/staging/duplication levers; the one
// structural difference vs the 874-TF m97 anchor is blocks-per-CU: m97 runs
// 3-4 small blocks whose waves cover each other's barrier stalls (m114
// cross-block overlap). R12-R14 had ONE 1024-thr block/CU -> whole-CU stall
// at every barrier (the un-decomposable ~3.5x step stretch). Now: BM=32,
// BK=32, 256-thr blocks (4 waves = 2 colpairs x 2 K-halves, R14's verified
// decomposition), 40 KB LDS (B dbuf 32K + x dbuf 8K) -> 4 blocks/CU,
// 16 waves/CU, 4 independent barrier domains. Same stage-ahead-2 skeleton,
// same op order as R14 -> bit-identical numerics.

typedef _Float16 half8v __attribute__((ext_vector_type(8)));
typedef float f32x16 __attribute__((ext_vector_type(16)));

constexpr int DIMK = 2048;
constexpr int NEXP = 64;
constexpr int BM   = 32;         // rows per block
constexpr int NCH  = DIMK / 32;  // 64 k-chunks of 32

__device__ __forceinline__ void async_load16(const void* g, void* l) {
    // global -> LDS DMA, 16B/lane; LDS dest = uniform base + lane*16,
    // GLOBAL source is per-lane (enables source-side swizzling, m173).
    __builtin_amdgcn_global_load_lds(
        (const __attribute__((address_space(1))) unsigned int*)g,
        (__attribute__((address_space(3))) unsigned int*)l, 16, 0, 0);
}

__device__ __forceinline__ bool gt_pair(float a, int ia, float b, int ib) {
    return (a > b) || (a == b && ia < ib);   // jax top_k: lower index wins ties
}

// ---- pre-kernel: split w' = 65536*[wg|wn] into 2 fp16 planes in 32x32x16
// B-frag order. Frag-block fb = c*16 + kh*8 + p*4 + nt  (1KB each, 1MB total):
// lane holds B[k = c*32 + kh*16 + (lane>>5)*8 + j][n' = nt*32 + (lane&31)]
// where nt 0,1 = w_gate cols 0..63 and nt 2,3 = w_noise cols 0..63.
__global__ __launch_bounds__(256)
void presplit_kernel(const float* __restrict__ wg, const float* __restrict__ wn,
                     _Float16* __restrict__ wsB)
{
    int gid  = blockIdx.x * 256 + threadIdx.x;   // 0..65535 = (fb, lane)
    int lane = gid & 63;
    int fb   = gid >> 6;          // 0..1023
    int nt   = fb & 3;
    int p    = (fb >> 2) & 1;
    int kh   = (fb >> 3) & 1;
    int c    = fb >> 4;
    const float* src = (nt < 2) ? (wg + nt * 32 + (lane & 31))
                                : (wn + (nt - 2) * 32 + (lane & 31));
    int kb = c * 32 + kh * 16 + ((lane >> 5) << 3);
    half8v hp;
    #pragma unroll
    for (int j = 0; j < 8; ++j) {
        float w = src[(size_t)(kb + j) * NEXP] * 65536.0f;
        _Float16 a = (_Float16)w;
        hp[j] = p ? (_Float16)(w - (float)a) : a;
    }
    *(half8v*)(wsB + (size_t)fb * 512 + lane * 8) = hp;
}

// ---- main kernel: 256 threads = 4 waves as (t = (w>>1)&1 colpair, ks = w&1 K-half).
// All waves cover the full 32 rows; wave owns [gate ntile t + noise ntile 2+t], K-half ks.
__global__ __launch_bounds__(256, 4)
void routing_mfma(const float* __restrict__ x, const _Float16* __restrict__ wsB,
                  const float* __restrict__ noise, float* __restrict__ out)
{
    // 40 KB: [Bs: 2 x 16KB][Xs: 2 x 4KB]; reused as epilogue scratch.
    // 4 blocks/CU x 40KB = 160KB (exact LDS fit).
    __shared__ __align__(16) char smem[40960];
    _Float16* Bs = (_Float16*)smem;              // [2][8192] halfs
    float*    Xs = (float*)(smem + 32768);       // [2][1024] floats

    const int tid  = threadIdx.x;
    const int lane = tid & 63;
    const int w    = tid >> 6;          // 0..3
    const int t    = (w >> 1) & 1;      // col pair (0,1)
    const int ks   = w & 1;             // K-half (0,1)
    const int m    = lane & 31;
    const int h    = lane >> 5;
    const int row0 = blockIdx.x * BM;

    f32x16 acc0 = {}, acc1 = {};        // gate ntile t / noise ntile 2+t (partial)

    // ---- staging: 5 DMA instrs per wave per step, all contiguous.
    // x LDS layout [32][32]f; source pre-swizzled in 16B slots:
    // phys slot = logical ^ (row&7)  (8 slots per row).
    const int lr  = lane >> 3;                    // row within this wave's 8-row group
    const int ssx = (lane & 7) ^ (lr & 7);        // inverse-swizzled 16B slot
    const float* xsrc = x + (size_t)(row0 + w * 8 + lr) * DIMK + ssx * 4;

    auto stage = [&](int s, int buf) {
        #pragma unroll
        for (int i = 0; i < 4; ++i) {     // B: 16 x 1KB frag blocks / step
            int j = w * 4 + i;
            async_load16(wsB + ((size_t)s * 16 + j) * 512 + lane * 8,
                         Bs + buf * 8192 + j * 512);
        }
        // x: 8 rows x 128B per instr; 4 instrs cover the 32x32f step tile
        async_load16(xsrc + s * 32, Xs + buf * 1024 + w * 256);
    };

    stage(0, 0);
    stage(1, 1);
    __syncthreads();

    const int rx7 = m & 7;

    for (int s = 0; s < NCH; ++s) {
        const int buf = s & 1;
        const float*    xrow = Xs + buf * 1024 + m * 32;
        const _Float16* bb   = Bs + buf * 8192 + (ks * 8) * 512 + lane * 8;

        // B frags (lane-linear 16B, conflict-free): kh=ks, p x {t, 2+t}
        half8v bH0 = *(const half8v*)(bb + (t    ) * 512);          // p0, gate
        half8v bH1 = *(const half8v*)(bb + (2 + t) * 512);          // p0, noise
        half8v bL0 = *(const half8v*)(bb + (4 + t    ) * 512);      // p1, gate
        half8v bL1 = *(const half8v*)(bb + (4 + 2 + t) * 512);      // p1, noise

        // x frags for kh=ks: logical 16B slot = ks*4 + h*2 + q, stored ^rx7
        float4 x0 = *(const float4*)(xrow + ((ks * 4 + h * 2 + 0) ^ rx7) * 4);
        float4 x1 = *(const float4*)(xrow + ((ks * 4 + h * 2 + 1) ^ rx7) * 4);

        // convert to split-fp16 planes (in registers)
        half8v aH, aL;
        {
            float f[8] = {x0.x, x0.y, x0.z, x0.w, x1.x, x1.y, x1.z, x1.w};
            #pragma unroll
            for (int j = 0; j < 8; ++j) {
                float v = f[j] * 1024.f;
                _Float16 a = (_Float16)v;
                aH[j] = a; aL[j] = (_Float16)(v - (float)a);
            }
        }

        // 3-pass split MFMA for both ntiles (kh=ks trio)
        acc0 = __builtin_amdgcn_mfma_f32_32x32x16_f16(aH, bH0, acc0, 0, 0, 0);
        acc0 = __builtin_amdgcn_mfma_f32_32x32x16_f16(aH, bL0, acc0, 0, 0, 0);
        acc0 = __builtin_amdgcn_mfma_f32_32x32x16_f16(aL, bH0, acc0, 0, 0, 0);
        acc1 = __builtin_amdgcn_mfma_f32_32x32x16_f16(aH, bH1, acc1, 0, 0, 0);
        acc1 = __builtin_amdgcn_mfma_f32_32x32x16_f16(aH, bL1, acc1, 0, 0, 0);
        acc1 = __builtin_amdgcn_mfma_f32_32x32x16_f16(aL, bH1, acc1, 0, 0, 0);

        // One barrier/step: drains our ds_reads and step s+1's DMAs (issued
        // a full step ago), then buf is safe to overwrite. The OTHER 3
        // resident blocks cover this block's barrier stall (m114 overlap).
        __syncthreads();
        if (s + 2 < NCH) stage(s + 2, buf);
    }

    // ---- epilogue ----
    // 32x32 C/D layout: col = lane&31 (expert within tile),
    // row = (reg&3) + 8*(reg>>2) + 4*(lane>>5). Unscale by 2^-26.
    // ks0 writes partials to scr; barrier; ks1 adds -> full values; barrier;
    // per-row combine + top2 + softmax + scatter.
    const float sc = 0x1p-26f;
    constexpr int SLD = 68;                 // 16B-aligned row stride (floats)
    float* scr = (float*)smem;              // [2 plane][32][SLD] = 17.4 KB
    {
        const int colb = t * 32 + m;
        if (ks == 0) {
            #pragma unroll
            for (int reg = 0; reg < 16; ++reg) {
                int rl = (reg & 3) + 8 * (reg >> 2) + 4 * h;     // 0..31
                scr[rl * SLD + colb]            = acc0[reg] * sc;
                scr[BM * SLD + rl * SLD + colb] = acc1[reg] * sc;
            }
        }
        __syncthreads();
        if (ks == 1) {
            #pragma unroll
            for (int reg = 0; reg < 16; ++reg) {
                int rl = (reg & 3) + 8 * (reg >> 2) + 4 * h;
                int ig = rl * SLD + colb;
                int in = BM * SLD + ig;
                scr[ig] += acc0[reg] * sc;
                scr[in] += acc1[reg] * sc;
            }
        }
        __syncthreads();
    }

    {
        int rr = tid >> 3;           // 0..31: row within block
        int s8 = tid & 7;            // 8-expert segment
        const float* gp = scr + rr * SLD + s8 * 8;
        const float* np = scr + BM * SLD + rr * SLD + s8 * 8;
        float4 g0 = *(const float4*)(gp);
        float4 g1 = *(const float4*)(gp + 4);
        float4 n0 = *(const float4*)(np);
        float4 n1 = *(const float4*)(np + 4);
        float4 z0 = *(const float4*)(noise + (size_t)(row0 + rr) * NEXP + s8 * 8);
        float4 z1 = *(const float4*)(noise + (size_t)(row0 + rr) * NEXP + s8 * 8 + 4);
        float gg[8] = {g0.x, g0.y, g0.z, g0.w, g1.x, g1.y, g1.z, g1.w};
        float nn[8] = {n0.x, n0.y, n0.z, n0.w, n1.x, n1.y, n1.z, n1.w};
        float zz[8] = {z0.x, z0.y, z0.z, z0.w, z1.x, z1.y, z1.z, z1.w};
        float v1 = -INFINITY, v2 = -INFINITY;
        int   i1 = 0x7ffffffe,  i2 = 0x7fffffff;
        #pragma unroll
        for (int j = 0; j < 8; ++j) {
            float nv = nn[j];
            float sp = fmaxf(nv, 0.f) + log1pf(expf(-fabsf(nv)));
            float vv = gg[j] + zz[j] * (sp + 0.01f);
            int   e  = s8 * 8 + j;
            if (gt_pair(vv, e, v1, i1)) { v2 = v1; i2 = i1; v1 = vv; i1 = e; }
            else if (gt_pair(vv, e, v2, i2)) { v2 = vv; i2 = e; }
        }
        #pragma unroll
        for (int mm = 1; mm <= 4; mm <<= 1) {    // butterfly over the 8-lane group
            float b1 = __shfl_xor(v1, mm); int ib1 = __shfl_xor(i1, mm);
            float b2 = __shfl_xor(v2, mm); int ib2 = __shfl_xor(i2, mm);
            if (gt_pair(b1, ib1, v1, i1)) {
                float o1 = v1; int oi1 = i1;
                v1 = b1; i1 = ib1;
                if (gt_pair(b2, ib2, o1, oi1)) { v2 = b2; i2 = ib2; }
                else                           { v2 = o1; i2 = oi1; }
            } else if (gt_pair(b1, ib1, v2, i2)) {
                v2 = b1; i2 = ib1;
            }
        }
        // all 8 lanes converge to the row's top2; softmax + scatter directly
        float te = expf(v2 - v1);     // <= 1
        float ga = 1.f / (1.f + te);
        float gb = te * ga;
        float* op = out + (size_t)(row0 + rr) * NEXP + s8 * 8;
        #pragma unroll
        for (int qq = 0; qq < 2; ++qq) {
            int e0 = s8 * 8 + qq * 4;
            float4 o;
            o.x = (e0 + 0 == i1) ? ga : ((e0 + 0 == i2) ? gb : 0.f);
            o.y = (e0 + 1 == i1) ? ga : ((e0 + 1 == i2) ? gb : 0.f);
            o.z = (e0 + 2 == i1) ? ga : ((e0 + 2 == i2) ? gb : 0.f);
            o.w = (e0 + 3 == i1) ? ga : ((e0 + 3 == i2) ? gb : 0.f);
            *(float4*)(op + qq * 4) = o;
        }
    }
}

extern "C" void kernel_launch(void* const* d_in, const int* in_sizes, int n_in,
                              void* d_out, int out_size, void* d_ws, size_t ws_size,
                              hipStream_t stream) {
    const float* x     = (const float*)d_in[0];
    const float* wg    = (const float*)d_in[1];
    const float* wn    = (const float*)d_in[2];
    const float* noise = (const float*)d_in[3];
    float* out = (float*)d_out;
    _Float16* wsB = (_Float16*)d_ws;   // needs 1024 * 1KB = 1 MB

    presplit_kernel<<<dim3(256), 256, 0, stream>>>(wg, wn, wsB);

    const int Brows = in_sizes[0] / DIMK;          // 32768
    dim3 grid(Brows / BM);                         // 1024 blocks -> 4/CU, 16 waves/CU
    routing_mfma<<<grid, 256, 0, stream>>>(x, wsB, noise, out);
}

// Round 13
// 398.010 us; speedup vs baseline: 1.0207x; 1.0207x over previous
//
#include <hip/hip_runtime.h>
#include <math.h>

// RoutingLayer fused via split-fp16 MFMA emulation of fp32 GEMM.
// routing = x@w_gate + noise*(softplus(x@w_noise)+0.01); out = scatter(softmax(top2)).
// x: 32768x2048 fp32, w_*: 2048x64 fp32, noise: 32768x64, out: 32768x64.
//
// R16 = R13 verbatim (best measured: 397.99us total, routing ~140us).
// Final lock-in. R4-R15 falsified every structural lever: pipeline depth
// (R5), occupancy (R6/R9), dep-breaking (R7), barrier-free (R10), fat steps
// (R13-null-delta), staging-instr count (R12), LDS/VALU work reduction
// (R14: -25%/-50% -> zero), blocks/CU 1-4 (R15). Routing is pinned at
// ~140us = approx the serial pipe-sum (MFMA-split 41 + LDS 45 + VALU 25 +
// VMEM 25); dur_us additionally carries a fixed ~258us harness re-poison
// tax (1GB ws fills). This variant: BM=128, BK=64, 1024 thr = 16 waves
// (4 rowgroups x 4 coltiles), 1 block/CU, 128KB LDS, stage-ahead-2,
// XOR-swizzled x source, in-register split-fp16 convert, 32x32x16 MFMA.

typedef _Float16 half8v __attribute__((ext_vector_type(8)));
typedef float f32x16 __attribute__((ext_vector_type(16)));

constexpr int DIMK = 2048;
constexpr int NEXP = 64;
constexpr int BM   = 128;        // rows per block
constexpr int BK   = 64;         // k per barrier-step
constexpr int NST  = DIMK / BK;  // 32 steps

__device__ __forceinline__ void async_load16(const void* g, void* l) {
    // global -> LDS DMA, 16B/lane; LDS dest = uniform base + lane*16,
    // GLOBAL source is per-lane (enables source-side swizzling, m173).
    __builtin_amdgcn_global_load_lds(
        (const __attribute__((address_space(1))) unsigned int*)g,
        (__attribute__((address_space(3))) unsigned int*)l, 16, 0, 0);
}

__device__ __forceinline__ bool gt_pair(float a, int ia, float b, int ib) {
    return (a > b) || (a == b && ia < ib);   // jax top_k: lower index wins ties
}

// ---- pre-kernel: split w' = 65536*[wg|wn] into 2 fp16 planes in 32x32x16
// B-frag order. Frag-block fb = c*16 + kh*8 + p*4 + nt  (1KB each, 1MB total):
// lane holds B[k = c*32 + kh*16 + (lane>>5)*8 + j][n' = nt*32 + (lane&31)]
// where nt 0,1 = w_gate cols 0..63 and nt 2,3 = w_noise cols 0..63.
__global__ __launch_bounds__(256)
void presplit_kernel(const float* __restrict__ wg, const float* __restrict__ wn,
                     _Float16* __restrict__ wsB)
{
    int gid  = blockIdx.x * 256 + threadIdx.x;   // 0..65535 = (fb, lane)
    int lane = gid & 63;
    int fb   = gid >> 6;          // 0..1023
    int nt   = fb & 3;
    int p    = (fb >> 2) & 1;
    int kh   = (fb >> 3) & 1;
    int c    = fb >> 4;
    const float* src = (nt < 2) ? (wg + nt * 32 + (lane & 31))
                                : (wn + (nt - 2) * 32 + (lane & 31));
    int kb = c * 32 + kh * 16 + ((lane >> 5) << 3);
    half8v hp;
    #pragma unroll
    for (int j = 0; j < 8; ++j) {
        float w = src[(size_t)(kb + j) * NEXP] * 65536.0f;
        _Float16 a = (_Float16)w;
        hp[j] = p ? (_Float16)(w - (float)a) : a;
    }
    *(half8v*)(wsB + (size_t)fb * 512 + lane * 8) = hp;
}

// ---- main kernel: 1024 threads = 16 waves as (rg = w>>2, t = w&3).
// Wave tile: 32 rows (rg) x 32 cols of tile t (0=gate-lo,1=gate-hi,2=noise-lo,3=noise-hi).
__global__ __launch_bounds__(1024, 4)
void routing_mfma(const float* __restrict__ x, const _Float16* __restrict__ wsB,
                  const float* __restrict__ noise, float* __restrict__ out)
{
    // 128 KB: [Bs: 2 x 32KB][Xs: 2 x 32KB]; reused as epilogue scratch.
    __shared__ __align__(16) char smem[131072];
    _Float16* Bs = (_Float16*)smem;              // [2][16384] halfs
    float*    Xs = (float*)(smem + 65536);       // [2][8192] floats

    const int tid  = threadIdx.x;
    const int lane = tid & 63;
    const int w    = tid >> 6;          // 0..15
    const int rg   = w >> 2;            // row group (0..3)
    const int t    = w & 3;             // col tile
    const int m    = lane & 31;
    const int h    = lane >> 5;
    const int row0 = blockIdx.x * BM;

    f32x16 acc = {};

    // ---- staging: 4 DMA instrs per wave per step, all contiguous 1KB.
    // x LDS layout [128][64]f; source pre-swizzled in 16B slots:
    // phys slot = logical ^ (row&7)  (XOR touches low 3 of 16 slots only).
    const int lr0 = (w * 2 + 0) * 4 + (lane >> 4);   // local rows for the 2 x-DMAs
    const int lr1 = (w * 2 + 1) * 4 + (lane >> 4);
    const int ss0 = (lane & 15) ^ (lr0 & 7);
    const int ss1 = (lane & 15) ^ (lr1 & 7);
    const float* xsrc0 = x + (size_t)(row0 + lr0) * DIMK + ss0 * 4;
    const float* xsrc1 = x + (size_t)(row0 + lr1) * DIMK + ss1 * 4;

    auto stage = [&](int s, int buf) {
        #pragma unroll
        for (int i = 0; i < 2; ++i) {     // B: 32 x 1KB frag blocks / step
            int j = w + i * 16;
            async_load16(wsB + ((size_t)s * 32 + j) * 512 + lane * 8,
                         Bs + buf * 16384 + j * 512);
        }
        // x: 4 rows x 256B per instr; 32 instrs cover the 128x64f step tile
        async_load16(xsrc0 + s * BK, Xs + buf * 8192 + (w * 2 + 0) * 256);
        async_load16(xsrc1 + s * BK, Xs + buf * 8192 + (w * 2 + 1) * 256);
    };

    stage(0, 0);
    stage(1, 1);
    __syncthreads();

    const int r   = rg * 32 + m;        // this lane's A-frag row (0..127)
    const int rx7 = r & 7;

    for (int s = 0; s < NST; ++s) {
        const int buf = s & 1;
        const float* xrow = Xs + buf * 8192 + r * 64;

        #pragma unroll
        for (int u = 0; u < 2; ++u) {             // two 32-k sub-chunks
            const _Float16* bb = Bs + buf * 16384 + u * 8192 + t * 512 + lane * 8;

            // B frags (lane-linear 16B, conflict-free)
            half8v bH0 = *(const half8v*)(bb);
            half8v bL0 = *(const half8v*)(bb + 2048);
            half8v bH1 = *(const half8v*)(bb + 4096);
            half8v bL1 = *(const half8v*)(bb + 6144);

            // x frags: logical 16B slot = u*8 + kh*4 + h*2 + q, stored ^rx7
            float4 x00 = *(const float4*)(xrow + ((u * 8 + h * 2 + 0) ^ rx7) * 4);
            float4 x01 = *(const float4*)(xrow + ((u * 8 + h * 2 + 1) ^ rx7) * 4);
            float4 x10 = *(const float4*)(xrow + ((u * 8 + 4 + h * 2 + 0) ^ rx7) * 4);
            float4 x11 = *(const float4*)(xrow + ((u * 8 + 4 + h * 2 + 1) ^ rx7) * 4);

            // convert to split-fp16 planes (in registers, per kh)
            half8v aH0, aL0, aH1, aL1;
            {
                float f[8] = {x00.x, x00.y, x00.z, x00.w, x01.x, x01.y, x01.z, x01.w};
                #pragma unroll
                for (int j = 0; j < 8; ++j) {
                    float v = f[j] * 1024.f;
                    _Float16 a = (_Float16)v;
                    aH0[j] = a; aL0[j] = (_Float16)(v - (float)a);
                }
            }
            {
                float f[8] = {x10.x, x10.y, x10.z, x10.w, x11.x, x11.y, x11.z, x11.w};
                #pragma unroll
                for (int j = 0; j < 8; ++j) {
                    float v = f[j] * 1024.f;
                    _Float16 a = (_Float16)v;
                    aH1[j] = a; aL1[j] = (_Float16)(v - (float)a);
                }
            }

            // 3-pass split MFMA per kh (same op order as R9/R11/R12)
            acc = __builtin_amdgcn_mfma_f32_32x32x16_f16(aH0, bH0, acc, 0, 0, 0);
            acc = __builtin_amdgcn_mfma_f32_32x32x16_f16(aH0, bL0, acc, 0, 0, 0);
            acc = __builtin_amdgcn_mfma_f32_32x32x16_f16(aL0, bH0, acc, 0, 0, 0);
            acc = __builtin_amdgcn_mfma_f32_32x32x16_f16(aH1, bH1, acc, 0, 0, 0);
            acc = __builtin_amdgcn_mfma_f32_32x32x16_f16(aH1, bL1, acc, 0, 0, 0);
            acc = __builtin_amdgcn_mfma_f32_32x32x16_f16(aL1, bH1, acc, 0, 0, 0);
        }

        // One barrier/step: drains our ds_reads and step s+1's DMAs (issued
        // a full step ago -> no stall), then buf is safe to overwrite.
        __syncthreads();
        if (s + 2 < NST) stage(s + 2, buf);
    }

    // ---- epilogue ----
    // 32x32 C/D layout: col = lane&31 (expert within tile),
    // row = (reg&3) + 8*(reg>>2) + 4*(lane>>5). Unscale by 2^-26.
    const float s = 0x1p-26f;
    constexpr int SLD = 68;                 // 16B-aligned row stride (floats)
    float* scr = (float*)smem;              // [2 plane][128][SLD] = 68 KB
    {
        const int pl   = (t >> 1) * BM * SLD;
        const int colb = (t & 1) * 32 + m;
        #pragma unroll
        for (int reg = 0; reg < 16; ++reg) {
            int rl = (reg & 3) + 8 * (reg >> 2) + 4 * h;     // 0..31
            scr[pl + (rg * 32 + rl) * SLD + colb] = acc[reg] * s;
        }
    }
    __syncthreads();

    {
        int rr = tid >> 3;           // 0..127: row within block
        int s8 = tid & 7;            // 8-expert segment
        const float* gp = scr + rr * SLD + s8 * 8;
        const float* np = scr + BM * SLD + rr * SLD + s8 * 8;
        float4 g0 = *(const float4*)(gp);
        float4 g1 = *(const float4*)(gp + 4);
        float4 n0 = *(const float4*)(np);
        float4 n1 = *(const float4*)(np + 4);
        float4 z0 = *(const float4*)(noise + (size_t)(row0 + rr) * NEXP + s8 * 8);
        float4 z1 = *(const float4*)(noise + (size_t)(row0 + rr) * NEXP + s8 * 8 + 4);
        float gg[8] = {g0.x, g0.y, g0.z, g0.w, g1.x, g1.y, g1.z, g1.w};
        float nn[8] = {n0.x, n0.y, n0.z, n0.w, n1.x, n1.y, n1.z, n1.w};
        float zz[8] = {z0.x, z0.y, z0.z, z0.w, z1.x, z1.y, z1.z, z1.w};
        float v1 = -INFINITY, v2 = -INFINITY;
        int   i1 = 0x7ffffffe,  i2 = 0x7fffffff;
        #pragma unroll
        for (int j = 0; j < 8; ++j) {
            float nv = nn[j];
            float sp = fmaxf(nv, 0.f) + log1pf(expf(-fabsf(nv)));
            float vv = gg[j] + zz[j] * (sp + 0.01f);
            int   e  = s8 * 8 + j;
            if (gt_pair(vv, e, v1, i1)) { v2 = v1; i2 = i1; v1 = vv; i1 = e; }
            else if (gt_pair(vv, e, v2, i2)) { v2 = vv; i2 = e; }
        }
        #pragma unroll
        for (int mm = 1; mm <= 4; mm <<= 1) {    // butterfly over the 8-lane group
            float b1 = __shfl_xor(v1, mm); int ib1 = __shfl_xor(i1, mm);
            float b2 = __shfl_xor(v2, mm); int ib2 = __shfl_xor(i2, mm);
            if (gt_pair(b1, ib1, v1, i1)) {
                float o1 = v1; int oi1 = i1;
                v1 = b1; i1 = ib1;
                if (gt_pair(b2, ib2, o1, oi1)) { v2 = b2; i2 = ib2; }
                else                           { v2 = o1; i2 = oi1; }
            } else if (gt_pair(b1, ib1, v2, i2)) {
                v2 = b1; i2 = ib1;
            }
        }
        // all 8 lanes converge to the row's top2; softmax + scatter directly
        float te = expf(v2 - v1);     // <= 1
        float ga = 1.f / (1.f + te);
        float gb = te * ga;
        float* op = out + (size_t)(row0 + rr) * NEXP + s8 * 8;
        #pragma unroll
        for (int qq = 0; qq < 2; ++qq) {
            int e0 = s8 * 8 + qq * 4;
            float4 o;
            o.x = (e0 + 0 == i1) ? ga : ((e0 + 0 == i2) ? gb : 0.f);
            o.y = (e0 + 1 == i1) ? ga : ((e0 + 1 == i2) ? gb : 0.f);
            o.z = (e0 + 2 == i1) ? ga : ((e0 + 2 == i2) ? gb : 0.f);
            o.w = (e0 + 3 == i1) ? ga : ((e0 + 3 == i2) ? gb : 0.f);
            *(float4*)(op + qq * 4) = o;
        }
    }
}

extern "C" void kernel_launch(void* const* d_in, const int* in_sizes, int n_in,
                              void* d_out, int out_size, void* d_ws, size_t ws_size,
                              hipStream_t stream) {
    const float* x     = (const float*)d_in[0];
    const float* wg    = (const float*)d_in[1];
    const float* wn    = (const float*)d_in[2];
    const float* noise = (const float*)d_in[3];
    float* out = (float*)d_out;
    _Float16* wsB = (_Float16*)d_ws;   // needs 1024 * 1KB = 1 MB

    presplit_kernel<<<dim3(256), 256, 0, stream>>>(wg, wn, wsB);

    const int Brows = in_sizes[0] / DIMK;          // 32768
    dim3 grid(Brows / BM);                         // 256 blocks -> 1/CU, 16 waves/CU
    routing_mfma<<<grid, 1024, 0, stream>>>(x, wsB, noise, out);
}